// Round 12
// baseline (43.844 us; speedup 1.0000x reference)
//
#include <hip/hip_runtime.h>
#include <math.h>

#define NB 256
#define NV 6890
#define NF 13776
#define NFP 16384               // faces padded to 4 * 4096, pad part = 15
#define NHD 20000
#define NHDP 20480              // samples padded to 5 * 4096, pad mask = 0
#define NPARTS 10
#define PY 120
#define PX 40
#define THREADS 1024
#define NWAVES (THREADS / 64)

// d_ws layout (bytes):
//   [0, 1024)            : per-batch distances (NB floats)
//   [1024, 1028)         : completion counter (reset by build_tabs)
//   [2048, +NFP*16)      : face table   int4{i0,i1,i2,part}   (pads part=15)
//   [.., +NHDP*16)       : sample table int4{i0,i1,i2,part}   (pads {0,0,0,0})
//   [.., +NHDP*16)       : sample bary  float4{w0,w1,w2,mask} (pads mask=0)
#define WS_DIST_OFF  0
#define WS_CTR_OFF   1024
#define WS_TABF_OFF  2048
#define WS_TABS_OFF  (WS_TABF_OFF + NFP * 16)
#define WS_TABW_OFF  (WS_TABS_OFF + NHDP * 16)
#define WS_NEEDED    (WS_TABW_OFF + NHDP * 16)

__device__ __forceinline__ float wred(float v) {
#pragma unroll
    for (int off = 32; off; off >>= 1) v += __shfl_down(v, off, 64);
    return v;
}

__global__ __launch_bounds__(256) void build_tabs(const int* __restrict__ faces,
                                                  const int* __restrict__ face_part,
                                                  const int* __restrict__ face_sample,
                                                  const float* __restrict__ bary_w,
                                                  int4* __restrict__ tabF,
                                                  int4* __restrict__ tabS,
                                                  float4* __restrict__ tabW,
                                                  unsigned int* __restrict__ ctr) {
    const int i = blockIdx.x * 256 + threadIdx.x;
    if (i == 0) *ctr = 0u;
    if (i < NF)
        tabF[i] = make_int4(faces[3 * i + 0], faces[3 * i + 1], faces[3 * i + 2], face_part[i]);
    else if (i < NFP)
        tabF[i] = make_int4(0, 0, 0, 15);            // pad: part 15 never accumulated
    if (i < NHD) {
        const int fs = face_sample[i];
        tabS[i] = make_int4(faces[3 * fs + 0], faces[3 * fs + 1], faces[3 * fs + 2],
                            face_part[fs]);
        tabW[i] = make_float4(bary_w[3 * i + 0], bary_w[3 * i + 1], bary_w[3 * i + 2], 1.0f);
    } else if (i < NHDP) {
        tabS[i] = make_int4(0, 0, 0, 0);
        tabW[i] = make_float4(0.0f, 0.0f, 0.0f, 0.0f);   // mask=0: contributes nothing
    }
}

__device__ __forceinline__ float tet_of(const float* __restrict__ svx,
                                        const float* __restrict__ svy,
                                        const float* __restrict__ svz, int4 q) {
    const float ax = svx[q.x], bx = svx[q.y], cx = svx[q.z];
    const float ay = svy[q.x], by = svy[q.y], cy = svy[q.z];
    const float az = svz[q.x], bz = svz[q.y], cz = svz[q.z];
    return (ax * (by * cz - bz * cy) + ay * (bz * cx - bx * cz) + az * (bx * cy - by * cx)) *
           (1.0f / 6.0f);
}

template <bool TAB>
__global__ __launch_bounds__(THREADS, 4) void stab_main(
    const float* __restrict__ vertices,    // [NB, NV, 3]
    const float* __restrict__ pressure,    // [NB, PY, PX]
    const float* __restrict__ bary_w,      // [NHD, 3]
    const int*   __restrict__ faces,       // [NF, 3]
    const int*   __restrict__ face_sample, // [NHD]
    const int*   __restrict__ face_part,   // [NF]
    const int4*  __restrict__ tabF,        // [NFP]
    const int4*  __restrict__ tabS,        // [NHDP]
    const float4* __restrict__ tabW,       // [NHDP]
    float* __restrict__ out,
    float* __restrict__ dist,
    unsigned int* __restrict__ ctr)
{
    const int b    = blockIdx.x;
    const int tid  = threadIdx.x;
    const int wave = tid >> 6;
    const int lane = tid & 63;

    __shared__ float svx[NV];
    __shared__ float svy[NV];
    __shared__ float svz[NV];
    __shared__ float red[NWAVES][12];
    __shared__ float ppv[NPARTS];         // one address per bank: broadcast, conflict-free
    __shared__ int   slast;

    // ---- stage vertices[b] into LDS (SoA) ----
    const float* vb = vertices + (size_t)b * (NV * 3);
    for (int v = tid; v < NV; v += THREADS) {
        svx[v] = vb[3 * v + 0];
        svy[v] = vb[3 * v + 1];
        svz[v] = vb[3 * v + 2];
    }
    __syncthreads();

    // ---- Phase A: tet volumes -> per-part sums (4 independent chains / iter) ----
    float pv[NPARTS];
#pragma unroll
    for (int p = 0; p < NPARTS; ++p) pv[p] = 0.0f;

    if constexpr (TAB) {
        for (int f0 = tid; f0 < NFP; f0 += 4 * THREADS) {
            const int4 q0 = tabF[f0];
            const int4 q1 = tabF[f0 + THREADS];
            const int4 q2 = tabF[f0 + 2 * THREADS];
            const int4 q3 = tabF[f0 + 3 * THREADS];
            const float t0 = tet_of(svx, svy, svz, q0);
            const float t1 = tet_of(svx, svy, svz, q1);
            const float t2 = tet_of(svx, svy, svz, q2);
            const float t3 = tet_of(svx, svy, svz, q3);
#pragma unroll
            for (int p = 0; p < NPARTS; ++p) {
                pv[p] += (q0.w == p) ? t0 : 0.0f;
                pv[p] += (q1.w == p) ? t1 : 0.0f;
                pv[p] += (q2.w == p) ? t2 : 0.0f;
                pv[p] += (q3.w == p) ? t3 : 0.0f;
            }
        }
    } else {
        for (int f = tid; f < NF; f += THREADS) {
            const int4 q = make_int4(faces[3 * f + 0], faces[3 * f + 1], faces[3 * f + 2],
                                     face_part[f]);
            const float t = tet_of(svx, svy, svz, q);
#pragma unroll
            for (int p = 0; p < NPARTS; ++p) pv[p] += (q.w == p) ? t : 0.0f;
        }
    }
#pragma unroll
    for (int p = 0; p < NPARTS; ++p) {
        const float r = wred(pv[p]);
        if (lane == 0) red[wave][p] = r;
    }
    __syncthreads();
    if (tid < NPARTS) {
        float s = 0.0f;
#pragma unroll
        for (int w = 0; w < NWAVES; ++w) s += red[w][tid];
        ppv[tid] = s;
    }
    __syncthreads();

    // ---- Phase B: blended samples -> COM + weighted-CoP sums ----
    float cnx = 0.f, cny = 0.f, cd = 0.f;
    float pnx = 0.f, pny = 0.f, pd = 0.f;

    if constexpr (TAB) {
        for (int n0 = tid; n0 < NHDP; n0 += 4 * THREADS) {
            const int4   q0 = tabS[n0];
            const int4   q1 = tabS[n0 + THREADS];
            const int4   q2 = tabS[n0 + 2 * THREADS];
            const int4   q3 = tabS[n0 + 3 * THREADS];
            const float4 w0 = tabW[n0];
            const float4 w1 = tabW[n0 + THREADS];
            const float4 w2 = tabW[n0 + 2 * THREADS];
            const float4 w3 = tabW[n0 + 3 * THREADS];

            const float hx0 = w0.x * svx[q0.x] + w0.y * svx[q0.y] + w0.z * svx[q0.z];
            const float hy0 = w0.x * svy[q0.x] + w0.y * svy[q0.y] + w0.z * svy[q0.z];
            const float hx1 = w1.x * svx[q1.x] + w1.y * svx[q1.y] + w1.z * svx[q1.z];
            const float hy1 = w1.x * svy[q1.x] + w1.y * svy[q1.y] + w1.z * svy[q1.z];
            const float hx2 = w2.x * svx[q2.x] + w2.y * svx[q2.y] + w2.z * svx[q2.z];
            const float hy2 = w2.x * svy[q2.x] + w2.y * svy[q2.y] + w2.z * svy[q2.z];
            const float hx3 = w3.x * svx[q3.x] + w3.y * svx[q3.y] + w3.z * svx[q3.z];
            const float hy3 = w3.x * svy[q3.x] + w3.y * svy[q3.y] + w3.z * svy[q3.z];

            const float vol0 = ppv[q0.w] * w0.w;
            const float vol1 = ppv[q1.w] * w1.w;
            const float vol2 = ppv[q2.w] * w2.w;
            const float vol3 = ppv[q3.w] * w3.w;

            const float pw0 = ((hy0 < 0.0f) ? (1.0f - 100.0f * hy0) : __expf(-10.0f * hy0)) * w0.w;
            const float pw1 = ((hy1 < 0.0f) ? (1.0f - 100.0f * hy1) : __expf(-10.0f * hy1)) * w1.w;
            const float pw2 = ((hy2 < 0.0f) ? (1.0f - 100.0f * hy2) : __expf(-10.0f * hy2)) * w2.w;
            const float pw3 = ((hy3 < 0.0f) ? (1.0f - 100.0f * hy3) : __expf(-10.0f * hy3)) * w3.w;

            cnx += hx0 * vol0 + hx1 * vol1 + hx2 * vol2 + hx3 * vol3;
            cny += hy0 * vol0 + hy1 * vol1 + hy2 * vol2 + hy3 * vol3;
            cd  += vol0 + vol1 + vol2 + vol3;
            pnx += hx0 * pw0 + hx1 * pw1 + hx2 * pw2 + hx3 * pw3;
            pny += hy0 * pw0 + hy1 * pw1 + hy2 * pw2 + hy3 * pw3;
            pd  += pw0 + pw1 + pw2 + pw3;
        }
    } else {
        for (int n = tid; n < NHD; n += THREADS) {
            const int fs = face_sample[n];
            const int i0 = faces[3 * fs + 0], i1 = faces[3 * fs + 1], i2 = faces[3 * fs + 2];
            const float w0 = bary_w[3 * n + 0], w1 = bary_w[3 * n + 1], w2 = bary_w[3 * n + 2];
            const float hx = w0 * svx[i0] + w1 * svx[i1] + w2 * svx[i2];
            const float hy = w0 * svy[i0] + w1 * svy[i1] + w2 * svy[i2];
            const float vol = ppv[face_part[fs]];
            cnx += hx * vol; cny += hy * vol; cd += vol;
            const float pw = (hy < 0.0f) ? (1.0f - 100.0f * hy) : __expf(-10.0f * hy);
            pnx += hx * pw; pny += hy * pw; pd += pw;
        }
    }

    // ---- pressure moments (float4) ----
    float pt = 0.f, pxs = 0.f, pys = 0.f;
    const float4* pb4 = (const float4*)(pressure + (size_t)b * (PY * PX));
    for (int i = tid; i < (PY * PX) / 4; i += THREADS) {
        const float4 v = pb4[i];
        const int idx = 4 * i;
        const float xb = (float)(idx % PX);
        const float yb = (float)(idx / PX);
        const float srow = v.x + v.y + v.z + v.w;
        pt  += srow;
        pxs += v.x * xb + v.y * (xb + 1.0f) + v.z * (xb + 2.0f) + v.w * (xb + 3.0f);
        pys += srow * yb;
    }

    // ---- block reduction of 9 scalars ----
    float vals[9] = {cnx, cny, cd, pnx, pny, pd, pt, pxs, pys};
#pragma unroll
    for (int k = 0; k < 9; ++k) {
        const float r = wred(vals[k]);
        if (lane == 0) red[wave][k] = r;
    }
    __syncthreads();

    if (tid == 0) {
        float s[9];
#pragma unroll
        for (int k = 0; k < 9; ++k) {
            float acc = 0.0f;
#pragma unroll
            for (int w = 0; w < NWAVES; ++w) acc += red[w][k];
            s[k] = acc;
        }
        const float comx  = s[0] / s[2];
        const float comy  = s[1] / s[2];
        const float copx  = s[3] / (s[5] + 1e-6f);
        const float copy_ = s[4] / (s[5] + 1e-6f);

        out[1 + 2 * b + 0] = comx * 48.0f;
        out[1 + 2 * b + 1] = (59.0f / 33.0f - comy) * 33.0f;
        out[1 + 2 * NB + 2 * b + 0] = (copx + 18.0f / 78.74f) * (100.0f * 0.7874f);
        out[1 + 2 * NB + 2 * b + 1] = (86.0f / 78.74f - copy_) * (100.0f * 0.7874f);

        const float total = (s[6] == 0.0f) ? 1e-8f : s[6];
        const float xc = s[7] / total;
        const float yc = s[8] / total;
        const float pcopx = 0.01f * (xc - 18.0f) / 0.7874f;
        const float pcopy = 0.01f * (86.0f - yc) / 0.7874f;

        const float dx = comx - pcopx;
        const float dy = comy - pcopy;
        dist[b] = sqrtf(dx * dx + dy * dy);
    }

    // ---- fused final reduce (TAB only): last block to finish sums dist[] ----
    if constexpr (TAB) {
        if (tid == 0) {
            __threadfence();                        // release dist[b]
            const unsigned int prev = atomicAdd(ctr, 1u);
            slast = (prev == NB - 1) ? 1 : 0;
        }
        __syncthreads();
        if (slast) {
            __threadfence();                        // acquire
            float v = 0.0f;
            if (tid < NB)
                v = __hip_atomic_load(&dist[tid], __ATOMIC_RELAXED,
                                      __HIP_MEMORY_SCOPE_AGENT);
            v = wred(v);
            if (lane == 0) red[wave][0] = v;
            __syncthreads();
            if (tid == 0) {
                float s = 0.0f;
#pragma unroll
                for (int w = 0; w < 4; ++w) s += red[w][0];   // waves 0-3 hold dist
                out[0] = s * (1.0f / NB);
            }
        }
    }
}

__global__ __launch_bounds__(256) void stab_reduce(const float* __restrict__ dist,
                                                   float* __restrict__ out) {
    const int tid = threadIdx.x;
    float v = dist[tid];
    v = wred(v);
    __shared__ float red[4];
    if ((tid & 63) == 0) red[tid >> 6] = v;
    __syncthreads();
    if (tid == 0) out[0] = (red[0] + red[1] + red[2] + red[3]) * (1.0f / 256.0f);
}

extern "C" void kernel_launch(void* const* d_in, const int* in_sizes, int n_in,
                              void* d_out, int out_size, void* d_ws, size_t ws_size,
                              hipStream_t stream) {
    const float* vertices    = (const float*)d_in[0];
    const float* pressure    = (const float*)d_in[1];
    const float* bary_w      = (const float*)d_in[2];
    const int*   faces       = (const int*)d_in[3];
    const int*   face_sample = (const int*)d_in[4];
    const int*   face_part   = (const int*)d_in[5];
    float* out = (float*)d_out;
    char*  ws  = (char*)d_ws;

    float*        dist = (float*)(ws + WS_DIST_OFF);
    unsigned int* ctr  = (unsigned int*)(ws + WS_CTR_OFF);

    if (ws_size >= (size_t)WS_NEEDED) {
        int4*   tabF = (int4*)(ws + WS_TABF_OFF);
        int4*   tabS = (int4*)(ws + WS_TABS_OFF);
        float4* tabW = (float4*)(ws + WS_TABW_OFF);
        build_tabs<<<(NHDP + 255) / 256, 256, 0, stream>>>(faces, face_part, face_sample,
                                                           bary_w, tabF, tabS, tabW, ctr);
        stab_main<true><<<NB, THREADS, 0, stream>>>(vertices, pressure, bary_w, faces,
                                                    face_sample, face_part, tabF, tabS, tabW,
                                                    out, dist, ctr);
    } else {
        stab_main<false><<<NB, THREADS, 0, stream>>>(vertices, pressure, bary_w, faces,
                                                     face_sample, face_part, nullptr, nullptr,
                                                     nullptr, out, dist, ctr);
        stab_reduce<<<1, 256, 0, stream>>>(dist, out);
    }
}

// Round 13
// 33.221 us; speedup vs baseline: 1.3198x; 1.3198x over previous
//
#include <hip/hip_runtime.h>
#include <math.h>

#define NB 256
#define NV 6890
#define NF 13776
#define NFP 16384               // faces padded to 4 * 4096, pad part = 15
#define NHD 20000
#define NHDP 20480              // samples padded to 5 * 4096, pad mask = 0
#define NPARTS 10
#define PY 120
#define PX 40
#define THREADS 1024
#define NWAVES (THREADS / 64)

// d_ws layout (bytes):
//   [0, 1024)            : per-batch distances (NB floats)
//   [1024, +NFP*16)      : face table   int4{i0,i1,i2,part}   (pads part=15)
//   [.., +NHDP*16)       : sample table int4{i0,i1,i2,part}   (pads {0,0,0,0})
//   [.., +NHDP*16)       : sample bary  float4{w0,w1,w2,mask} (pads mask=0)
#define WS_DIST_OFF  0
#define WS_TABF_OFF  1024
#define WS_TABS_OFF  (WS_TABF_OFF + NFP * 16)
#define WS_TABW_OFF  (WS_TABS_OFF + NHDP * 16)
#define WS_NEEDED    (WS_TABW_OFF + NHDP * 16)

__device__ __forceinline__ float wred(float v) {
#pragma unroll
    for (int off = 32; off; off >>= 1) v += __shfl_down(v, off, 64);
    return v;
}

__global__ __launch_bounds__(256) void build_tabs(const int* __restrict__ faces,
                                                  const int* __restrict__ face_part,
                                                  const int* __restrict__ face_sample,
                                                  const float* __restrict__ bary_w,
                                                  int4* __restrict__ tabF,
                                                  int4* __restrict__ tabS,
                                                  float4* __restrict__ tabW) {
    const int i = blockIdx.x * 256 + threadIdx.x;
    if (i < NF)
        tabF[i] = make_int4(faces[3 * i + 0], faces[3 * i + 1], faces[3 * i + 2], face_part[i]);
    else if (i < NFP)
        tabF[i] = make_int4(0, 0, 0, 15);            // pad: part 15 never accumulated
    if (i < NHD) {
        const int fs = face_sample[i];
        tabS[i] = make_int4(faces[3 * fs + 0], faces[3 * fs + 1], faces[3 * fs + 2],
                            face_part[fs]);
        tabW[i] = make_float4(bary_w[3 * i + 0], bary_w[3 * i + 1], bary_w[3 * i + 2], 1.0f);
    } else if (i < NHDP) {
        tabS[i] = make_int4(0, 0, 0, 0);
        tabW[i] = make_float4(0.0f, 0.0f, 0.0f, 0.0f);   // mask=0: contributes nothing
    }
}

__device__ __forceinline__ float tet_of(const float2* __restrict__ svxy,
                                        const float* __restrict__ svz, int4 q) {
    const float2 a = svxy[q.x];
    const float2 b = svxy[q.y];
    const float2 c = svxy[q.z];
    const float az = svz[q.x], bz = svz[q.y], cz = svz[q.z];
    return (a.x * (b.y * cz - bz * c.y) + a.y * (bz * c.x - b.x * cz) +
            az * (b.x * c.y - b.y * c.x)) * (1.0f / 6.0f);
}

template <bool TAB>
__global__ __launch_bounds__(THREADS, 4) void stab_main(
    const float* __restrict__ vertices,    // [NB, NV, 3]
    const float* __restrict__ pressure,    // [NB, PY, PX]
    const float* __restrict__ bary_w,      // [NHD, 3]
    const int*   __restrict__ faces,       // [NF, 3]
    const int*   __restrict__ face_sample, // [NHD]
    const int*   __restrict__ face_part,   // [NF]
    const int4*  __restrict__ tabF,        // [NFP]
    const int4*  __restrict__ tabS,        // [NHDP]
    const float4* __restrict__ tabW,       // [NHDP]
    float* __restrict__ out,
    float* __restrict__ dist)
{
    const int b    = blockIdx.x;
    const int tid  = threadIdx.x;
    const int wave = tid >> 6;
    const int lane = tid & 63;

    __shared__ float2 svxy[NV];           // 55120 B: b64 gathers, half the instrs
    __shared__ float  svz[NV];            // 27560 B
    __shared__ float  red[NWAVES][12];
    __shared__ float  ppv[NPARTS];        // one address per bank: broadcast, conflict-free

    // ---- stage vertices[b] into LDS (xy packed, z separate) ----
    const float* vb = vertices + (size_t)b * (NV * 3);
    for (int v = tid; v < NV; v += THREADS) {
        svxy[v] = make_float2(vb[3 * v + 0], vb[3 * v + 1]);
        svz[v]  = vb[3 * v + 2];
    }
    __syncthreads();

    // ---- Phase A: tet volumes -> per-part sums (4 independent chains / iter) ----
    float pv[NPARTS];
#pragma unroll
    for (int p = 0; p < NPARTS; ++p) pv[p] = 0.0f;

    if constexpr (TAB) {
        for (int f0 = tid; f0 < NFP; f0 += 4 * THREADS) {
            const int4 q0 = tabF[f0];
            const int4 q1 = tabF[f0 + THREADS];
            const int4 q2 = tabF[f0 + 2 * THREADS];
            const int4 q3 = tabF[f0 + 3 * THREADS];
            const float t0 = tet_of(svxy, svz, q0);
            const float t1 = tet_of(svxy, svz, q1);
            const float t2 = tet_of(svxy, svz, q2);
            const float t3 = tet_of(svxy, svz, q3);
#pragma unroll
            for (int p = 0; p < NPARTS; ++p) {
                pv[p] += (q0.w == p) ? t0 : 0.0f;
                pv[p] += (q1.w == p) ? t1 : 0.0f;
                pv[p] += (q2.w == p) ? t2 : 0.0f;
                pv[p] += (q3.w == p) ? t3 : 0.0f;
            }
        }
    } else {
        for (int f = tid; f < NF; f += THREADS) {
            const int4 q = make_int4(faces[3 * f + 0], faces[3 * f + 1], faces[3 * f + 2],
                                     face_part[f]);
            const float t = tet_of(svxy, svz, q);
#pragma unroll
            for (int p = 0; p < NPARTS; ++p) pv[p] += (q.w == p) ? t : 0.0f;
        }
    }
#pragma unroll
    for (int p = 0; p < NPARTS; ++p) {
        const float r = wred(pv[p]);
        if (lane == 0) red[wave][p] = r;
    }
    __syncthreads();
    if (tid < NPARTS) {
        float s = 0.0f;
#pragma unroll
        for (int w = 0; w < NWAVES; ++w) s += red[w][tid];
        ppv[tid] = s;
    }
    __syncthreads();

    // ---- Phase B: blended samples -> COM + weighted-CoP sums ----
    float cnx = 0.f, cny = 0.f, cd = 0.f;
    float pnx = 0.f, pny = 0.f, pd = 0.f;

    if constexpr (TAB) {
        for (int n0 = tid; n0 < NHDP; n0 += 4 * THREADS) {
            const int4   q0 = tabS[n0];
            const int4   q1 = tabS[n0 + THREADS];
            const int4   q2 = tabS[n0 + 2 * THREADS];
            const int4   q3 = tabS[n0 + 3 * THREADS];
            const float4 w0 = tabW[n0];
            const float4 w1 = tabW[n0 + THREADS];
            const float4 w2 = tabW[n0 + 2 * THREADS];
            const float4 w3 = tabW[n0 + 3 * THREADS];

            const float2 a0 = svxy[q0.x], b0 = svxy[q0.y], c0 = svxy[q0.z];
            const float2 a1 = svxy[q1.x], b1 = svxy[q1.y], c1 = svxy[q1.z];
            const float2 a2 = svxy[q2.x], b2 = svxy[q2.y], c2 = svxy[q2.z];
            const float2 a3 = svxy[q3.x], b3 = svxy[q3.y], c3 = svxy[q3.z];

            const float hx0 = w0.x * a0.x + w0.y * b0.x + w0.z * c0.x;
            const float hy0 = w0.x * a0.y + w0.y * b0.y + w0.z * c0.y;
            const float hx1 = w1.x * a1.x + w1.y * b1.x + w1.z * c1.x;
            const float hy1 = w1.x * a1.y + w1.y * b1.y + w1.z * c1.y;
            const float hx2 = w2.x * a2.x + w2.y * b2.x + w2.z * c2.x;
            const float hy2 = w2.x * a2.y + w2.y * b2.y + w2.z * c2.y;
            const float hx3 = w3.x * a3.x + w3.y * b3.x + w3.z * c3.x;
            const float hy3 = w3.x * a3.y + w3.y * b3.y + w3.z * c3.y;

            const float vol0 = ppv[q0.w] * w0.w;
            const float vol1 = ppv[q1.w] * w1.w;
            const float vol2 = ppv[q2.w] * w2.w;
            const float vol3 = ppv[q3.w] * w3.w;

            const float pw0 = ((hy0 < 0.0f) ? (1.0f - 100.0f * hy0) : __expf(-10.0f * hy0)) * w0.w;
            const float pw1 = ((hy1 < 0.0f) ? (1.0f - 100.0f * hy1) : __expf(-10.0f * hy1)) * w1.w;
            const float pw2 = ((hy2 < 0.0f) ? (1.0f - 100.0f * hy2) : __expf(-10.0f * hy2)) * w2.w;
            const float pw3 = ((hy3 < 0.0f) ? (1.0f - 100.0f * hy3) : __expf(-10.0f * hy3)) * w3.w;

            cnx += hx0 * vol0 + hx1 * vol1 + hx2 * vol2 + hx3 * vol3;
            cny += hy0 * vol0 + hy1 * vol1 + hy2 * vol2 + hy3 * vol3;
            cd  += vol0 + vol1 + vol2 + vol3;
            pnx += hx0 * pw0 + hx1 * pw1 + hx2 * pw2 + hx3 * pw3;
            pny += hy0 * pw0 + hy1 * pw1 + hy2 * pw2 + hy3 * pw3;
            pd  += pw0 + pw1 + pw2 + pw3;
        }
    } else {
        for (int n = tid; n < NHD; n += THREADS) {
            const int fs = face_sample[n];
            const int i0 = faces[3 * fs + 0], i1 = faces[3 * fs + 1], i2 = faces[3 * fs + 2];
            const float w0 = bary_w[3 * n + 0], w1 = bary_w[3 * n + 1], w2 = bary_w[3 * n + 2];
            const float2 a = svxy[i0], bb = svxy[i1], c = svxy[i2];
            const float hx = w0 * a.x + w1 * bb.x + w2 * c.x;
            const float hy = w0 * a.y + w1 * bb.y + w2 * c.y;
            const float vol = ppv[face_part[fs]];
            cnx += hx * vol; cny += hy * vol; cd += vol;
            const float pw = (hy < 0.0f) ? (1.0f - 100.0f * hy) : __expf(-10.0f * hy);
            pnx += hx * pw; pny += hy * pw; pd += pw;
        }
    }

    // ---- pressure moments (float4) ----
    float pt = 0.f, pxs = 0.f, pys = 0.f;
    const float4* pb4 = (const float4*)(pressure + (size_t)b * (PY * PX));
    for (int i = tid; i < (PY * PX) / 4; i += THREADS) {
        const float4 v = pb4[i];
        const int idx = 4 * i;
        const float xb = (float)(idx % PX);
        const float yb = (float)(idx / PX);
        const float srow = v.x + v.y + v.z + v.w;
        pt  += srow;
        pxs += v.x * xb + v.y * (xb + 1.0f) + v.z * (xb + 2.0f) + v.w * (xb + 3.0f);
        pys += srow * yb;
    }

    // ---- block reduction of 9 scalars ----
    float vals[9] = {cnx, cny, cd, pnx, pny, pd, pt, pxs, pys};
#pragma unroll
    for (int k = 0; k < 9; ++k) {
        const float r = wred(vals[k]);
        if (lane == 0) red[wave][k] = r;
    }
    __syncthreads();

    if (tid == 0) {
        float s[9];
#pragma unroll
        for (int k = 0; k < 9; ++k) {
            float acc = 0.0f;
#pragma unroll
            for (int w = 0; w < NWAVES; ++w) acc += red[w][k];
            s[k] = acc;
        }
        const float comx  = s[0] / s[2];
        const float comy  = s[1] / s[2];
        const float copx  = s[3] / (s[5] + 1e-6f);
        const float copy_ = s[4] / (s[5] + 1e-6f);

        out[1 + 2 * b + 0] = comx * 48.0f;
        out[1 + 2 * b + 1] = (59.0f / 33.0f - comy) * 33.0f;
        out[1 + 2 * NB + 2 * b + 0] = (copx + 18.0f / 78.74f) * (100.0f * 0.7874f);
        out[1 + 2 * NB + 2 * b + 1] = (86.0f / 78.74f - copy_) * (100.0f * 0.7874f);

        const float total = (s[6] == 0.0f) ? 1e-8f : s[6];
        const float xc = s[7] / total;
        const float yc = s[8] / total;
        const float pcopx = 0.01f * (xc - 18.0f) / 0.7874f;
        const float pcopy = 0.01f * (86.0f - yc) / 0.7874f;

        const float dx = comx - pcopx;
        const float dy = comy - pcopy;
        dist[b] = sqrtf(dx * dx + dy * dy);
    }
}

__global__ __launch_bounds__(256) void stab_reduce(const float* __restrict__ dist,
                                                   float* __restrict__ out) {
    const int tid = threadIdx.x;
    float v = dist[tid];
    v = wred(v);
    __shared__ float red[4];
    if ((tid & 63) == 0) red[tid >> 6] = v;
    __syncthreads();
    if (tid == 0) out[0] = (red[0] + red[1] + red[2] + red[3]) * (1.0f / 256.0f);
}

extern "C" void kernel_launch(void* const* d_in, const int* in_sizes, int n_in,
                              void* d_out, int out_size, void* d_ws, size_t ws_size,
                              hipStream_t stream) {
    const float* vertices    = (const float*)d_in[0];
    const float* pressure    = (const float*)d_in[1];
    const float* bary_w      = (const float*)d_in[2];
    const int*   faces       = (const int*)d_in[3];
    const int*   face_sample = (const int*)d_in[4];
    const int*   face_part   = (const int*)d_in[5];
    float* out = (float*)d_out;
    char*  ws  = (char*)d_ws;

    float* dist = (float*)(ws + WS_DIST_OFF);

    if (ws_size >= (size_t)WS_NEEDED) {
        int4*   tabF = (int4*)(ws + WS_TABF_OFF);
        int4*   tabS = (int4*)(ws + WS_TABS_OFF);
        float4* tabW = (float4*)(ws + WS_TABW_OFF);
        build_tabs<<<(NHDP + 255) / 256, 256, 0, stream>>>(faces, face_part, face_sample,
                                                           bary_w, tabF, tabS, tabW);
        stab_main<true><<<NB, THREADS, 0, stream>>>(vertices, pressure, bary_w, faces,
                                                    face_sample, face_part, tabF, tabS, tabW,
                                                    out, dist);
    } else {
        stab_main<false><<<NB, THREADS, 0, stream>>>(vertices, pressure, bary_w, faces,
                                                     face_sample, face_part, nullptr, nullptr,
                                                     nullptr, out, dist);
    }
    stab_reduce<<<1, 256, 0, stream>>>(dist, out);
}